// Round 17
// baseline (105.158 us; speedup 1.0000x reference)
//
#include <hip/hip_runtime.h>

#define NH 4
#define HD 64
#define IN_DIM 128
#define NEG_SLOPE 0.2f
#define BN 256          // dst nodes per bucket (multisplit granularity)
#define NBMAX 512       // max buckets (n <= 131072)
#define SLAB 5120       // records per bucket slab (mean 4092, sigma ~64 -> +16 sigma)
#define CHUNK 4096      // edges per multisplit block
#define EPT (CHUNK/512) // edges per thread in multisplit (512-thread blocks)
#define HSBUF 4096      // per-half sort capacity (mean 2046, sigma ~45 -> +45 sigma)
#define NGEMM 391       // GEMM role blocks in k_combo

typedef short bf8 __attribute__((ext_vector_type(8)));   // 8 bf16 in 4 VGPRs
typedef float f4  __attribute__((ext_vector_type(4)));

__device__ inline unsigned short f2bf(float f) {   // RNE fp32 -> bf16
  unsigned u = __float_as_uint(f);
  u += 0x7FFFu + ((u >> 16) & 1u);
  return (unsigned short)(u >> 16);
}

// ---- P1: combined dispatch. Roles by blockIdx:
//   [0, ngemm)            : MFMA projection feat/el/er
//   [ngemm, ngemm+nchunks): multisplit into fixed-capacity 256-node bucket slabs
//   ngemm+nchunks         : tiny ee[t][h] table
__global__ __launch_bounds__(512) void k_combo(
    const float* __restrict__ x, const float* __restrict__ fcW,
    const float* __restrict__ attn_l, const float* __restrict__ attn_r,
    unsigned short* __restrict__ featb, float4* __restrict__ el4, float4* __restrict__ er4,
    const int* __restrict__ src, const int* __restrict__ dst, const int* __restrict__ et,
    int* __restrict__ cntg, unsigned* __restrict__ ebuf,
    const float* __restrict__ edge_emb, const float* __restrict__ fc_e_W,
    const float* __restrict__ attn_e, float* __restrict__ ee,
    int n, int ne, int nb, int ngemm, int nchunks)
{
  __shared__ union {
    struct {
      int scnt[NBMAX];                 // 2 KB
      unsigned short sbase[NBMAX];     // 1 KB
      unsigned short goff[NBMAX];      // 1 KB (slab offset, clamped <= SLAB)
      unsigned sbuf[CHUNK];            // 16 KB
      int wsm[8], wbs[8];
    } m;
    unsigned short wt[HD][IN_DIM + 8]; // 17.4 KB (GEMM role)
    float sef[8][128];                 // 4 KB (ee role)
  } sm;

  const int t = threadIdx.x;
  const int lane = t & 63, wv = t >> 6;

  if (blockIdx.x < ngemm) {
    // ======== GEMM role: feat(bf16) = x @ fc_W + el/er; 8 waves = 128 rows/iter ========
    for (int idx = t; idx < IN_DIM * HD; idx += 512) {
      int k = idx >> 6, j = idx & 63;
      sm.wt[j][k] = f2bf(fcW[idx]);
    }
    __syncthreads();

    const int lr = lane & 15;
    const int lg = lane >> 4;
    float al[NH], ar[NH];
#pragma unroll
    for (int h = 0; h < NH; ++h) { al[h] = attn_l[h * 16 + lr]; ar[h] = attn_r[h * 16 + lr]; }

    const int ntp = (n + 127) >> 7;     // tile pairs of 128 rows
    for (int tp = blockIdx.x; tp < ntp; tp += ngemm) {
      const int rowbase = tp * 128 + wv * 16;
      int arow = rowbase + lr;
      if (arow >= n) arow = n - 1;                   // clamp; stores predicated
      const float* xp = x + (size_t)arow * IN_DIM + lg * 8;

      f4 acc[4] = {};                                // one per n-tile (= head)
#pragma unroll
      for (int kc = 0; kc < 4; ++kc) {
        float4 a0 = *(const float4*)(xp + kc * 32);
        float4 a1 = *(const float4*)(xp + kc * 32 + 4);
        bf8 af;
        af[0] = (short)f2bf(a0.x); af[1] = (short)f2bf(a0.y);
        af[2] = (short)f2bf(a0.z); af[3] = (short)f2bf(a0.w);
        af[4] = (short)f2bf(a1.x); af[5] = (short)f2bf(a1.y);
        af[6] = (short)f2bf(a1.z); af[7] = (short)f2bf(a1.w);
#pragma unroll
        for (int nt = 0; nt < 4; ++nt) {
          bf8 bfr = *(const bf8*)&sm.wt[nt * 16 + lr][kc * 32 + lg * 8];
          acc[nt] = __builtin_amdgcn_mfma_f32_16x16x32_bf16(af, bfr, acc[nt], 0, 0, 0);
        }
      }

#pragma unroll
      for (int r = 0; r < 4; ++r) {
        int grow = rowbase + lg * 4 + r;
        bool ok = grow < n;
        if (ok) {
#pragma unroll
          for (int nt = 0; nt < 4; ++nt)
            featb[(size_t)grow * HD + nt * 16 + lr] = f2bf(acc[nt][r]);
        }
        float pl[NH], pr[NH];
#pragma unroll
        for (int h = 0; h < NH; ++h) { pl[h] = acc[h][r] * al[h]; pr[h] = acc[h][r] * ar[h]; }
#pragma unroll
        for (int off = 1; off < 16; off <<= 1) {
#pragma unroll
          for (int h = 0; h < NH; ++h) {
            pl[h] += __shfl_xor(pl[h], off);
            pr[h] += __shfl_xor(pr[h], off);
          }
        }
        if (ok && lr == 0) {
          el4[grow] = make_float4(pl[0], pl[1], pl[2], pl[3]);
          er4[grow] = make_float4(pr[0], pr[1], pr[2], pr[3]);
        }
      }
    }
    return;
  }

  if (blockIdx.x >= ngemm + nchunks) {
    // ======== ee role ========
    if (t < 128) {
      for (int r = 0; r < 8; ++r) {
        float acc = 0.f;
#pragma unroll
        for (int k = 0; k < 32; ++k) acc = fmaf(edge_emb[r * 32 + k], fc_e_W[k * 128 + t], acc);
        sm.sef[r][t] = acc;
      }
    }
    __syncthreads();
    if (t < 32) {
      int r = t >> 2, h = t & 3;
      float acc = 0.f;
#pragma unroll
      for (int e2 = 0; e2 < 32; ++e2) acc += sm.sef[r][h * 32 + e2] * attn_e[h * 32 + e2];
      ee[r * NH + h] = acc;
    }
    return;
  }

  // ======== multisplit role: rec = src|et<<17|dlocal<<20 into fixed slabs (bin = dst>>8) ========
  const int base = (blockIdx.x - ngemm) * CHUNK;
  for (int i = t; i < nb; i += 512) sm.m.scnt[i] = 0;
  __syncthreads();
  unsigned pk[EPT], rc[EPT];
#pragma unroll
  for (int i = 0; i < EPT; ++i) {
    int e = base + i * 512 + t;
    pk[i] = 0xFFFFFFFFu;
    if (e < ne) {
      int d = dst[e];
      int bin = d >> 8;
      rc[i] = (unsigned)src[e] | ((unsigned)et[e] << 17) | ((unsigned)(d & 255) << 20);
      int slot = atomicAdd(&sm.m.scnt[bin], 1);
      pk[i] = ((unsigned)slot << 9) | (unsigned)bin;
    }
  }
  __syncthreads();
  // scan: thread t owns bin t
  int c = (t < nb) ? sm.m.scnt[t] : 0;
  int inc = c;
#pragma unroll
  for (int off = 1; off < 64; off <<= 1) {
    int v = __shfl_up(inc, off);
    if (lane >= off) inc += v;
  }
  if (lane == 63) sm.m.wsm[wv] = inc;
  __syncthreads();
  if (t == 0) { int r = 0; for (int k = 0; k < 8; ++k) { sm.m.wbs[k] = r; r += sm.m.wsm[k]; } }
  __syncthreads();
  int ex = sm.m.wbs[wv] + inc - c;
  if (t < nb) {
    sm.m.sbase[t] = (unsigned short)ex;
    if (c > 0) {
      int raw = atomicAdd(&cntg[t], c);
      sm.m.goff[t] = (unsigned short)(raw < SLAB ? raw : SLAB);
    }
  }
  __syncthreads();
#pragma unroll
  for (int i = 0; i < EPT; ++i) {
    if (pk[i] != 0xFFFFFFFFu) {
      int bin = (int)(pk[i] & 511u);
      int slot = (int)(pk[i] >> 9);
      sm.m.sbuf[(int)sm.m.sbase[bin] + slot] = rc[i];
    }
  }
  __syncthreads();
  // copy-out to slabs: 8 record-lanes per bin, 64 bins per block-iteration
  const int sub = lane >> 3, rl = lane & 7;
  for (int b0 = wv * 8 + sub; b0 < nb; b0 += 64) {
    int cnt = sm.m.scnt[b0];
    if (cnt > 0) {
      int sb = (int)sm.m.sbase[b0];
      int go = (int)sm.m.goff[b0];
      int allowed = SLAB - go;                 // capacity clamp (overflow -> fallback)
      if (allowed > cnt) allowed = cnt;
      unsigned* gp = ebuf + (size_t)b0 * SLAB + go;
      for (int i2 = rl; i2 < allowed; i2 += 8)
        gp[i2] = sm.m.sbuf[sb + i2];
    }
  }
}

// ---- P2: half-bucket LDS counting sort + register-accum aggregation (512 thr, 2 blocks/bucket) ----
__global__ __launch_bounds__(512) void k_sortagg(
    const unsigned* __restrict__ ebuf, const int* __restrict__ cntg,
    const float* __restrict__ el, const float4* __restrict__ er4,
    const float* __restrict__ eeg, const uint4* __restrict__ featq,
    const int* __restrict__ src, const int* __restrict__ dst, const int* __restrict__ et,
    float4* __restrict__ out4, int n, int ne)
{
  __shared__ unsigned sbuf[HSBUF];     // 16 KB
  __shared__ int cnt[128];             // half-bucket histogram
  __shared__ int sb[129];              // segment bases
  __shared__ float s_er[128][NH];      // 2 KB
  __shared__ float s_ee[32];
  __shared__ int wsum[2];
  __shared__ int ovf;
  const int t = threadIdx.x;
  const int bb = blockIdx.x >> 1;      // bucket
  const int hh = blockIdx.x & 1;       // half (dlocal bit 7)
  const int node0 = bb * BN + hh * 128;
  const int count0 = cntg[bb];
  const int count = count0 < SLAB ? count0 : SLAB;
  const int beg = bb * SLAB;
  const int end = beg + count;
  for (int i = t; i < 128; i += 512) cnt[i] = 0;
  {
    int i = t & 127;
    if (t < 128) {
      int node = node0 + i;
      float4 v = (node < n) ? er4[node] : make_float4(0.f, 0.f, 0.f, 0.f);
      s_er[i][0] = v.x; s_er[i][1] = v.y; s_er[i][2] = v.z; s_er[i][3] = v.w;
    }
  }
  if (t < 32) s_ee[t] = eeg[t];
  if (t == 0) ovf = (count0 > SLAB) ? 1 : 0;
  __syncthreads();

  const int lane = t & 63, wv = t >> 6;    // 8 waves
  const int q = lane >> 3;      // 8 records in flight per wave
  const int l = lane & 7;       // dim octet: dims 8l..8l+7
  const int h = l >> 1;         // head for this lane's dims

  // pass 1: filtered histogram; cache record + within-bin slot in registers
  unsigned rr_[SLAB / 512], pk_[SLAB / 512];
#pragma unroll
  for (int j = 0; j < SLAB / 512; ++j) {
    int i = beg + j * 512 + t;
    pk_[j] = 0xFFFFFFFFu;
    if (i < end) {
      unsigned r = ebuf[i];
      unsigned dl = r >> 20;
      if ((int)(dl >> 7) == hh) {
        rr_[j] = r;
        unsigned bin = dl & 127u;
        unsigned slot = (unsigned)atomicAdd(&cnt[bin], 1);
        pk_[j] = (slot << 7) | bin;
      }
    }
  }
  __syncthreads();
  // scan 128 bins with waves 0-1
  int cc = 0, inc = 0;
  if (t < 128) {
    cc = cnt[t];
    inc = cc;
#pragma unroll
    for (int off = 1; off < 64; off <<= 1) {
      int v = __shfl_up(inc, off);
      if (lane >= off) inc += v;
    }
    if (lane == 63) wsum[wv] = inc;
  }
  __syncthreads();
  if (t < 128) {
    int ex = (wv ? wsum[0] : 0) + inc - cc;
    sb[t] = ex;
    if (t == 127) { sb[128] = ex + cc; if (ex + cc > HSBUF) atomicOr(&ovf, 1); }
  }
  __syncthreads();
  const bool sorted = (ovf == 0);
  if (sorted) {
    // pass 2: place from registers (no atomics, no re-read)
#pragma unroll
    for (int j = 0; j < SLAB / 512; ++j) {
      if (pk_[j] != 0xFFFFFFFFu)
        sbuf[sb[pk_[j] & 127u] + (int)(pk_[j] >> 7)] = rr_[j];
    }
    __syncthreads();
  }

  // aggregation: wave wv owns local dsts [wv*16, wv*16+16)
  for (int ld = wv * 16; ld < wv * 16 + 16; ++ld) {
    float erh = s_er[ld][h];
    float a0 = 0.f, a1 = 0.f, a2 = 0.f, a3 = 0.f;
    float a4 = 0.f, a5 = 0.f, a6 = 0.f, a7 = 0.f, den = 0.f;
    if (sorted) {
      const int s0 = sb[ld], s1 = sb[ld + 1];
      for (int i = s0 + q; i < s1; i += 8) {
        unsigned r = sbuf[i];
        int s  = (int)(r & 0x1FFFFu);
        int tt = (int)((r >> 17) & 7u);
        float sv = el[s * NH + h] + erh + s_ee[tt * NH + h];
        sv = sv > 0.f ? sv : NEG_SLOPE * sv;
        float p = __expf(sv);
        den += p;
        uint4 u = featq[(size_t)s * 8 + l];
        a0 = fmaf(p, __uint_as_float(u.x << 16), a0);
        a1 = fmaf(p, __uint_as_float(u.x & 0xFFFF0000u), a1);
        a2 = fmaf(p, __uint_as_float(u.y << 16), a2);
        a3 = fmaf(p, __uint_as_float(u.y & 0xFFFF0000u), a3);
        a4 = fmaf(p, __uint_as_float(u.z << 16), a4);
        a5 = fmaf(p, __uint_as_float(u.z & 0xFFFF0000u), a5);
        a6 = fmaf(p, __uint_as_float(u.w << 16), a6);
        a7 = fmaf(p, __uint_as_float(u.w & 0xFFFF0000u), a7);
      }
    } else {
      // fallback (statistically never): filtered rescan of the raw edge list
      int node = node0 + ld;
      for (int i = q; i < ne; i += 8) {
        if (dst[i] != node) continue;
        int s  = src[i];
        int tt = et[i];
        float sv = el[s * NH + h] + erh + s_ee[tt * NH + h];
        sv = sv > 0.f ? sv : NEG_SLOPE * sv;
        float p = __expf(sv);
        den += p;
        uint4 u = featq[(size_t)s * 8 + l];
        a0 = fmaf(p, __uint_as_float(u.x << 16), a0);
        a1 = fmaf(p, __uint_as_float(u.x & 0xFFFF0000u), a1);
        a2 = fmaf(p, __uint_as_float(u.y << 16), a2);
        a3 = fmaf(p, __uint_as_float(u.y & 0xFFFF0000u), a3);
        a4 = fmaf(p, __uint_as_float(u.z << 16), a4);
        a5 = fmaf(p, __uint_as_float(u.z & 0xFFFF0000u), a5);
        a6 = fmaf(p, __uint_as_float(u.w << 16), a6);
        a7 = fmaf(p, __uint_as_float(u.w & 0xFFFF0000u), a7);
      }
    }
#pragma unroll
    for (int off = 8; off <= 32; off <<= 1) {
      den += __shfl_xor(den, off);
      a0 += __shfl_xor(a0, off); a1 += __shfl_xor(a1, off);
      a2 += __shfl_xor(a2, off); a3 += __shfl_xor(a3, off);
      a4 += __shfl_xor(a4, off); a5 += __shfl_xor(a5, off);
      a6 += __shfl_xor(a6, off); a7 += __shfl_xor(a7, off);
    }
    if (q == 0) {
      int node = node0 + ld;
      if (node < n) {
        float inv = den > 0.f ? 1.f / den : 0.f;
        float4* op = out4 + (size_t)node * 16 + l * 2;
        op[0] = make_float4(a0 * inv, a1 * inv, a2 * inv, a3 * inv);
        op[1] = make_float4(a4 * inv, a5 * inv, a6 * inv, a7 * inv);
      }
    }
  }
}

extern "C" void kernel_launch(void* const* d_in, const int* in_sizes, int n_in,
                              void* d_out, int out_size, void* d_ws, size_t ws_size,
                              hipStream_t stream)
{
  const float* x        = (const float*)d_in[0];
  const int*   src      = (const int*)d_in[1];
  const int*   dst      = (const int*)d_in[2];
  const int*   etype    = (const int*)d_in[3];
  const float* fcW      = (const float*)d_in[4];
  const float* fceW     = (const float*)d_in[5];
  const float* edge_emb = (const float*)d_in[6];
  const float* attn_l   = (const float*)d_in[7];
  const float* attn_r   = (const float*)d_in[8];
  const float* attn_e   = (const float*)d_in[9];
  float* out = (float*)d_out;

  const int n  = in_sizes[0] / IN_DIM;      // 100000
  const int ne = in_sizes[1];               // 1600000
  const int nb = (n + BN - 1) / BN;         // 391 buckets
  const int nchunks = (ne + CHUNK - 1) / CHUNK;   // 391 multisplit blocks

  char* ws = (char*)d_ws;
  size_t off = 0;
  unsigned short* featb = (unsigned short*)(ws + off); off += (size_t)n * HD * sizeof(unsigned short);
  float* el    = (float*)(ws + off); off += (size_t)n * NH * sizeof(float);
  float* er    = (float*)(ws + off); off += (size_t)n * NH * sizeof(float);
  float* ee    = (float*)(ws + off); off += 256;
  int* cntg    = (int*)(ws + off);   off += NBMAX * sizeof(int);
  unsigned* ebuf = (unsigned*)(ws + off); off += (size_t)NBMAX * SLAB * sizeof(unsigned);

  hipMemsetAsync(cntg, 0, NBMAX * sizeof(int), stream);

  k_combo<<<NGEMM + nchunks + 1, 512, 0, stream>>>(
      x, fcW, attn_l, attn_r, featb, (float4*)el, (float4*)er,
      src, dst, etype, cntg, ebuf, edge_emb, fceW, attn_e, ee,
      n, ne, nb, NGEMM, nchunks);
  k_sortagg<<<2 * nb, 512, 0, stream>>>(ebuf, cntg, el, (const float4*)er, ee,
                                        (const uint4*)featb, src, dst, etype,
                                        (float4*)out, n, ne);
}